// Round 11
// baseline (337.830 us; speedup 1.0000x reference)
//
#include <hip/hip_runtime.h>
#include <hip/hip_fp16.h>

#define NN 100000
#define EE 1600000
#define K1 128
#define HH 64

#define NB 196        // buckets = ceil(NN / 512)
#define BW 512        // dsts per bucket (dst >> 9)
#define CAP 12288     // per-bucket capacity (mean 8192, +~45 sigma)
#define CHUNK 4096    // edges per binA block

typedef float f32x4 __attribute__((ext_vector_type(4)));
typedef unsigned int u32x4 __attribute__((ext_vector_type(4)));
typedef unsigned int u32x2 __attribute__((ext_vector_type(2)));

// ---------------- setup ----------------

__global__ void k_zeroB(int* __restrict__ bcursor) {
    bcursor[threadIdx.x] = 0;   // 256 >= NB
}

// Phase A: single-pass bin-by-bucket. Chunk staged in LDS (one ei read),
// 4-byte packed entries: (dst&511)<<17 | src  (src < 2^17).
__global__ __launch_bounds__(256) void k_binA(const int* __restrict__ ei,
                                              int* __restrict__ bcursor,
                                              unsigned* __restrict__ binned) {
    __shared__ int ls[CHUNK];
    __shared__ int ld[CHUNK];
    __shared__ int lh[256], lbase[256], lcur[256];
    int t = threadIdx.x;
    int e0 = blockIdx.x * CHUNK;
    int n = min(CHUNK, EE - e0);
    lh[t] = 0;
    __syncthreads();
    for (int j = t; j < n; j += 256) {
        int s = ei[e0 + j];
        int d = ei[EE + e0 + j];
        ls[j] = s; ld[j] = d;
        atomicAdd(&lh[d >> 9], 1);
    }
    __syncthreads();
    lbase[t] = (lh[t] > 0) ? atomicAdd(&bcursor[t], lh[t]) : 0;
    lcur[t] = 0;
    __syncthreads();
    for (int j = t; j < n; j += 256) {
        int d = ld[j];
        int b = d >> 9;
        int pos = lbase[b] + atomicAdd(&lcur[b], 1);
        binned[(size_t)b * CAP + pos] = ((unsigned)(d & 511) << 17) | (unsigned)ls[j];
    }
}

// Phase B: one block per bucket. Hist over 512 dsts -> scan -> offsets + dinv,
// then dense scatter of src into the final csr segment.
__global__ __launch_bounds__(256) void k_sortB(const unsigned* __restrict__ binned,
                                               const int* __restrict__ bcursor,
                                               int* __restrict__ offsets,
                                               float* __restrict__ dinv,
                                               int* __restrict__ csr_src) {
    __shared__ int lhist[BW], excl[BW], lcur[BW];
    __shared__ int sbase_sm;
    int t = threadIdx.x;
    int b = blockIdx.x;
    int lo = b << 9;
    int cnt = bcursor[b];

    lcur[t] = (t < b) ? bcursor[t] : 0;
    __syncthreads();
    for (int off = 128; off > 0; off >>= 1) {
        if (t < off) lcur[t] += lcur[t + off];
        __syncthreads();
    }
    if (t == 0) sbase_sm = lcur[0];
    for (int j = t; j < BW; j += 256) lhist[j] = 0;
    __syncthreads();
    int sbase = sbase_sm;
    const unsigned* bp = binned + (size_t)b * CAP;
    for (int i = t; i < cnt; i += 256)
        atomicAdd(&lhist[bp[i] >> 17], 1);
    __syncthreads();
    if (t < 64) {
        int v[8], s = 0;
#pragma unroll
        for (int i = 0; i < 8; i++) { v[i] = lhist[t * 8 + i]; s += v[i]; }
        int run = s;
        for (int off = 1; off < 64; off <<= 1) {
            int u = __shfl_up(run, off);
            if (t >= off) run += u;
        }
        int base = run - s;
#pragma unroll
        for (int i = 0; i < 8; i++) { excl[t * 8 + i] = base; base += v[i]; }
    }
    __syncthreads();
    for (int j = t; j < BW; j += 256) {
        int d = lo + j;
        if (d < NN) {
            offsets[d] = sbase + excl[j];
            dinv[d] = rsqrtf((float)lhist[j] + 1.0f);
        }
    }
    if (b == NB - 1 && t == 0) offsets[NN] = sbase + cnt;   // sentinel == E
    for (int j = t; j < BW; j += 256) lcur[j] = 0;
    __syncthreads();
    for (int i = t; i < cnt; i += 256) {
        unsigned u = bp[i];
        int d = (int)(u >> 17);
        int slot = excl[d] + atomicAdd(&lcur[d], 1);
        csr_src[sbase + slot] = (int)(u & 0x1FFFF);
    }
}

// ---------------- GEMM: h[n][64] = (x[n][K] @ W[K][64]) * dinv[n], fp16 out ----
// Streaming inputs loaded nontemporal (don't evict the h-table / future y16).

template <int K, int TM, bool INH>
__global__ __launch_bounds__(256) void k_gemm(const void* __restrict__ xin,
                                              const float* __restrict__ W,
                                              const float* __restrict__ dinv,
                                              __half* __restrict__ h) {
    __shared__ float Wl[K * 64];
    __shared__ float xs[TM * K];
    int t = threadIdx.x;
    int base = blockIdx.x * TM;
    for (int i = t; i < K * 16; i += 256)
        reinterpret_cast<float4*>(Wl)[i] = reinterpret_cast<const float4*>(W)[i];
    {
        const int NF4 = TM * K / 4;
        const int RF4 = K / 4;
        for (int i = t; i < NF4; i += 256) {
            int r = i / RF4, c = i - r * RF4;
            int gr = base + r; if (gr >= NN) gr = NN - 1;
            float4 v;
            if (INH) {
                u32x2 u = __builtin_nontemporal_load(
                    reinterpret_cast<const u32x2*>(xin) + (size_t)gr * RF4 + c);
                unsigned ua = u[0], ub = u[1];
                __half2 h01 = *reinterpret_cast<__half2*>(&ua);
                __half2 h23 = *reinterpret_cast<__half2*>(&ub);
                float2 f01 = __half22float2(h01);
                float2 f23 = __half22float2(h23);
                v = make_float4(f01.x, f01.y, f23.x, f23.y);
            } else {
                f32x4 u = __builtin_nontemporal_load(
                    reinterpret_cast<const f32x4*>(xin) + (size_t)gr * RF4 + c);
                v = make_float4(u[0], u[1], u[2], u[3]);
            }
            reinterpret_cast<float4*>(xs)[i] = v;
        }
    }
    __syncthreads();

    int lane = t & 63;
    int wid = t >> 6;
    const int RW = TM / 4;
    int r0 = wid * RW;
    float acc[RW];
#pragma unroll
    for (int r = 0; r < RW; r++) acc[r] = 0.f;

    for (int k = 0; k < K; k += 4) {
        float w0 = Wl[(k + 0) * 64 + lane];
        float w1 = Wl[(k + 1) * 64 + lane];
        float w2 = Wl[(k + 2) * 64 + lane];
        float w3 = Wl[(k + 3) * 64 + lane];
#pragma unroll
        for (int r = 0; r < RW; r++) {
            const float4 xv = *reinterpret_cast<const float4*>(&xs[(r0 + r) * K + k]);
            acc[r] = fmaf(xv.x, w0, acc[r]);
            acc[r] = fmaf(xv.y, w1, acc[r]);
            acc[r] = fmaf(xv.z, w2, acc[r]);
            acc[r] = fmaf(xv.w, w3, acc[r]);
        }
    }
    __half* hp = h + ((size_t)base + r0) * 64 + lane;
#pragma unroll
    for (int r = 0; r < RW; r++) {
        int row = base + r0 + r;
        if (row < NN) hp[r * 64] = __float2half(acc[r] * dinv[row]);
    }
}

// ---------------- aggregation V4 + nontemporal output ----------------
// h pre-scaled by dinv[src], zero row at index NN. wave = 1 node; group g
// (8 lanes) owns slots 4g..4g+3; lane p loads uint4 = 8 fp16 feats. Output
// stored nontemporal (streaming; protect the h-table in L2).

template <bool BN, bool OUTH>
__global__ __launch_bounds__(256) void k_agg(const __half* __restrict__ h,
                                             const int* __restrict__ csr_src,
                                             const int* __restrict__ offsets,
                                             const float* __restrict__ dinv,
                                             const float* __restrict__ bias,
                                             const float* __restrict__ g,
                                             const float* __restrict__ beta,
                                             const float* __restrict__ rm,
                                             const float* __restrict__ rv,
                                             void* __restrict__ outp) {
    int node = (blockIdx.x * 256 + threadIdx.x) >> 6;
    int lane = threadIdx.x & 63;
    int grp = lane >> 3;     // 0..7: slot group
    int p = lane & 7;        // uint4 index; feats 8p..8p+7
    int start = offsets[node];
    int len = offsets[node + 1] - start;
    const int* ep = csr_src + start;
    const uint4* hp4 = reinterpret_cast<const uint4*>(h);

    float a0 = 0.f, a1 = 0.f, a2 = 0.f, a3 = 0.f;
    float a4 = 0.f, a5 = 0.f, a6 = 0.f, a7 = 0.f;
    for (int i = 0; i < len; i += 32) {
        int s0, s1, s2, s3;
        {
            int sl = i + 4 * grp;
            int cl0 = sl     < len ? sl     : len - 1;
            int cl1 = sl + 1 < len ? sl + 1 : len - 1;
            int cl2 = sl + 2 < len ? sl + 2 : len - 1;
            int cl3 = sl + 3 < len ? sl + 3 : len - 1;
            int v0 = __builtin_nontemporal_load(ep + cl0);
            int v1 = __builtin_nontemporal_load(ep + cl1);
            int v2 = __builtin_nontemporal_load(ep + cl2);
            int v3 = __builtin_nontemporal_load(ep + cl3);
            s0 = (sl     < len) ? v0 : NN;   // zero row when masked
            s1 = (sl + 1 < len) ? v1 : NN;
            s2 = (sl + 2 < len) ? v2 : NN;
            s3 = (sl + 3 < len) ? v3 : NN;
        }
        uint4 d0 = hp4[(size_t)s0 * 8 + p];
        uint4 d1 = hp4[(size_t)s1 * 8 + p];
        uint4 d2 = hp4[(size_t)s2 * 8 + p];
        uint4 d3 = hp4[(size_t)s3 * 8 + p];
        const __half2* h0 = reinterpret_cast<const __half2*>(&d0);
        const __half2* h1 = reinterpret_cast<const __half2*>(&d1);
        const __half2* h2 = reinterpret_cast<const __half2*>(&d2);
        const __half2* h3 = reinterpret_cast<const __half2*>(&d3);
#pragma unroll
        for (int j = 0; j < 4; j++) {
            __half2 q = __hadd2(__hadd2(h0[j], h1[j]), __hadd2(h2[j], h3[j]));
            float2 f = __half22float2(q);
            if (j == 0) { a0 += f.x; a1 += f.y; }
            else if (j == 1) { a2 += f.x; a3 += f.y; }
            else if (j == 2) { a4 += f.x; a5 += f.y; }
            else { a6 += f.x; a7 += f.y; }
        }
    }
#pragma unroll
    for (int d = 8; d <= 32; d <<= 1) {
        a0 += __shfl_xor(a0, d); a1 += __shfl_xor(a1, d);
        a2 += __shfl_xor(a2, d); a3 += __shfl_xor(a3, d);
        a4 += __shfl_xor(a4, d); a5 += __shfl_xor(a5, d);
        a6 += __shfl_xor(a6, d); a7 += __shfl_xor(a7, d);
    }

    if (grp == 0) {
        uint4 sd = hp4[(size_t)node * 8 + p];
        const __half2* sh = reinterpret_cast<const __half2*>(&sd);
        float2 f;
        f = __half22float2(sh[0]); a0 += f.x; a1 += f.y;
        f = __half22float2(sh[1]); a2 += f.x; a3 += f.y;
        f = __half22float2(sh[2]); a4 += f.x; a5 += f.y;
        f = __half22float2(sh[3]); a6 += f.x; a7 += f.y;
        float di = dinv[node];
        float4 b0 = reinterpret_cast<const float4*>(bias)[2 * p];
        float4 b1 = reinterpret_cast<const float4*>(bias)[2 * p + 1];
        float r0 = fmaf(a0, di, b0.x), r1 = fmaf(a1, di, b0.y);
        float r2 = fmaf(a2, di, b0.z), r3 = fmaf(a3, di, b0.w);
        float r4 = fmaf(a4, di, b1.x), r5 = fmaf(a5, di, b1.y);
        float r6 = fmaf(a6, di, b1.z), r7 = fmaf(a7, di, b1.w);
        if (BN) {
            float4 g0 = reinterpret_cast<const float4*>(g)[2 * p];
            float4 g1 = reinterpret_cast<const float4*>(g)[2 * p + 1];
            float4 t0 = reinterpret_cast<const float4*>(beta)[2 * p];
            float4 t1 = reinterpret_cast<const float4*>(beta)[2 * p + 1];
            float4 m0 = reinterpret_cast<const float4*>(rm)[2 * p];
            float4 m1 = reinterpret_cast<const float4*>(rm)[2 * p + 1];
            float4 v0 = reinterpret_cast<const float4*>(rv)[2 * p];
            float4 v1 = reinterpret_cast<const float4*>(rv)[2 * p + 1];
            r0 = fmaxf(fmaf(r0 - m0.x, g0.x * rsqrtf(v0.x + 1e-5f), t0.x), 0.f);
            r1 = fmaxf(fmaf(r1 - m0.y, g0.y * rsqrtf(v0.y + 1e-5f), t0.y), 0.f);
            r2 = fmaxf(fmaf(r2 - m0.z, g0.z * rsqrtf(v0.z + 1e-5f), t0.z), 0.f);
            r3 = fmaxf(fmaf(r3 - m0.w, g0.w * rsqrtf(v0.w + 1e-5f), t0.w), 0.f);
            r4 = fmaxf(fmaf(r4 - m1.x, g1.x * rsqrtf(v1.x + 1e-5f), t1.x), 0.f);
            r5 = fmaxf(fmaf(r5 - m1.y, g1.y * rsqrtf(v1.y + 1e-5f), t1.y), 0.f);
            r6 = fmaxf(fmaf(r6 - m1.z, g1.z * rsqrtf(v1.z + 1e-5f), t1.z), 0.f);
            r7 = fmaxf(fmaf(r7 - m1.w, g1.w * rsqrtf(v1.w + 1e-5f), t1.w), 0.f);
        }
        if (OUTH) {
            __half2 o0; o0.x = __float2half_rn(r0); o0.y = __float2half_rn(r1);
            __half2 o1; o1.x = __float2half_rn(r2); o1.y = __float2half_rn(r3);
            __half2 o2; o2.x = __float2half_rn(r4); o2.y = __float2half_rn(r5);
            __half2 o3; o3.x = __float2half_rn(r6); o3.y = __float2half_rn(r7);
            u32x4 o;
            o[0] = *reinterpret_cast<unsigned*>(&o0);
            o[1] = *reinterpret_cast<unsigned*>(&o1);
            o[2] = *reinterpret_cast<unsigned*>(&o2);
            o[3] = *reinterpret_cast<unsigned*>(&o3);
            __builtin_nontemporal_store(
                o, reinterpret_cast<u32x4*>(outp) + (size_t)node * 8 + p);
        } else {
            f32x4 oa, ob;
            oa[0] = r0; oa[1] = r1; oa[2] = r2; oa[3] = r3;
            ob[0] = r4; ob[1] = r5; ob[2] = r6; ob[3] = r7;
            __builtin_nontemporal_store(
                oa, reinterpret_cast<f32x4*>(outp) + (size_t)node * 16 + 2 * p);
            __builtin_nontemporal_store(
                ob, reinterpret_cast<f32x4*>(outp) + (size_t)node * 16 + 2 * p + 1);
        }
    }
}

// ---------------- launch ----------------

extern "C" void kernel_launch(void* const* d_in, const int* in_sizes, int n_in,
                              void* d_out, int out_size, void* d_ws, size_t ws_size,
                              hipStream_t stream) {
    const float* x = (const float*)d_in[0];
    const int* ei = (const int*)d_in[1];        // int32 per harness contract, [2][E]
    const float* W1 = (const float*)d_in[2];
    const float* b1 = (const float*)d_in[3];
    const float* W2 = (const float*)d_in[4];
    const float* b2 = (const float*)d_in[5];
    const float* W3 = (const float*)d_in[6];
    const float* b3 = (const float*)d_in[7];
    const float* g1 = (const float*)d_in[8];
    const float* be1 = (const float*)d_in[9];
    const float* rm1 = (const float*)d_in[10];
    const float* rv1 = (const float*)d_in[11];
    const float* g2 = (const float*)d_in[12];
    const float* be2 = (const float*)d_in[13];
    const float* rm2 = (const float*)d_in[14];
    const float* rv2 = (const float*)d_in[15];
    float* out = (float*)d_out;

    char* ws = (char*)d_ws;
    size_t off = 0;
    auto alloc = [&](size_t bytes) -> void* {
        void* p = ws + off;
        off = (off + bytes + 255) & ~(size_t)255;
        return p;
    };
    int* bcursor = (int*)alloc(256 * 4);
    int* offsets = (int*)alloc((size_t)(NN + 1) * 4);
    float* dinv = (float*)alloc((size_t)NN * 4);
    unsigned* binned = (unsigned*)alloc((size_t)NB * CAP * 4);
    int* csr_src = (int*)alloc((size_t)EE * 4);
    __half* h16 = (__half*)alloc((size_t)(NN + 1) * 64 * 2);   // +1 zero row
    __half* y16 = (__half*)alloc((size_t)(NN + 1) * 64 * 2);

    // zero rows at index NN (gather target for masked slots)
    hipMemsetAsync(h16 + (size_t)NN * 64, 0, 128, stream);
    hipMemsetAsync(y16 + (size_t)NN * 64, 0, 128, stream);

    k_zeroB<<<1, 256, 0, stream>>>(bcursor);
    k_binA<<<(EE + CHUNK - 1) / CHUNK, 256, 0, stream>>>(ei, bcursor, binned);
    k_sortB<<<NB, 256, 0, stream>>>(binned, bcursor, offsets, dinv, csr_src);

    // layer 1: K=128, TM=32, fp32 input
    k_gemm<K1, 32, false><<<NN / 32, 256, 0, stream>>>(x, W1, dinv, h16);
    k_agg<true, true><<<NN * 64 / 256, 256, 0, stream>>>(h16, csr_src, offsets, dinv,
                                                         b1, g1, be1, rm1, rv1, y16);
    // layer 2: K=64, TM=64, fp16 input
    k_gemm<HH, 64, true><<<(NN + 63) / 64, 256, 0, stream>>>(y16, W2, dinv, h16);
    k_agg<true, true><<<NN * 64 / 256, 256, 0, stream>>>(h16, csr_src, offsets, dinv,
                                                         b2, g2, be2, rm2, rv2, y16);
    // layer 3: fp32 output to d_out
    k_gemm<HH, 64, true><<<(NN + 63) / 64, 256, 0, stream>>>(y16, W3, dinv, h16);
    k_agg<false, false><<<NN * 64 / 256, 256, 0, stream>>>(h16, csr_src, offsets, dinv,
                                                           b3, b3, b3, b3, b3, out);
}

// Round 12
// 324.187 us; speedup vs baseline: 1.0421x; 1.0421x over previous
//
#include <hip/hip_runtime.h>
#include <hip/hip_fp16.h>

#define NN 100000
#define EE 1600000
#define K1 128
#define HH 64

#define NB 196        // buckets = ceil(NN / 512)
#define BW 512        // dsts per bucket (dst >> 9)
#define CAP 12288     // per-bucket capacity (mean 8192, +~45 sigma)
#define CHUNK 4096    // edges per binA block

// ---------------- setup ----------------

// Phase A: single-pass bin-by-bucket. Chunk staged in LDS (one ei read),
// 4-byte packed entries: (dst&511)<<17 | src  (src < 2^17).
__global__ __launch_bounds__(256) void k_binA(const int* __restrict__ ei,
                                              int* __restrict__ bcursor,
                                              unsigned* __restrict__ binned) {
    __shared__ int ls[CHUNK];
    __shared__ int ld[CHUNK];
    __shared__ int lh[256], lbase[256], lcur[256];
    int t = threadIdx.x;
    int e0 = blockIdx.x * CHUNK;
    int n = min(CHUNK, EE - e0);
    lh[t] = 0;
    __syncthreads();
    for (int j = t; j < n; j += 256) {
        int s = ei[e0 + j];
        int d = ei[EE + e0 + j];
        ls[j] = s; ld[j] = d;
        atomicAdd(&lh[d >> 9], 1);
    }
    __syncthreads();
    lbase[t] = (lh[t] > 0) ? atomicAdd(&bcursor[t], lh[t]) : 0;
    lcur[t] = 0;
    __syncthreads();
    for (int j = t; j < n; j += 256) {
        int d = ld[j];
        int b = d >> 9;
        int pos = lbase[b] + atomicAdd(&lcur[b], 1);
        binned[(size_t)b * CAP + pos] = ((unsigned)(d & 511) << 17) | (unsigned)ls[j];
    }
}

// Phase B: one block per bucket. Hist over 512 dsts -> scan -> offsets + dinv,
// then dense scatter of src into the final csr segment.
__global__ __launch_bounds__(256) void k_sortB(const unsigned* __restrict__ binned,
                                               const int* __restrict__ bcursor,
                                               int* __restrict__ offsets,
                                               float* __restrict__ dinv,
                                               int* __restrict__ csr_src) {
    __shared__ int lhist[BW], excl[BW], lcur[BW];
    __shared__ int sbase_sm;
    int t = threadIdx.x;
    int b = blockIdx.x;
    int lo = b << 9;
    int cnt = bcursor[b];

    lcur[t] = (t < b) ? bcursor[t] : 0;
    __syncthreads();
    for (int off = 128; off > 0; off >>= 1) {
        if (t < off) lcur[t] += lcur[t + off];
        __syncthreads();
    }
    if (t == 0) sbase_sm = lcur[0];
    for (int j = t; j < BW; j += 256) lhist[j] = 0;
    __syncthreads();
    int sbase = sbase_sm;
    const unsigned* bp = binned + (size_t)b * CAP;
    for (int i = t; i < cnt; i += 256)
        atomicAdd(&lhist[bp[i] >> 17], 1);
    __syncthreads();
    if (t < 64) {
        int v[8], s = 0;
#pragma unroll
        for (int i = 0; i < 8; i++) { v[i] = lhist[t * 8 + i]; s += v[i]; }
        int run = s;
        for (int off = 1; off < 64; off <<= 1) {
            int u = __shfl_up(run, off);
            if (t >= off) run += u;
        }
        int base = run - s;
#pragma unroll
        for (int i = 0; i < 8; i++) { excl[t * 8 + i] = base; base += v[i]; }
    }
    __syncthreads();
    for (int j = t; j < BW; j += 256) {
        int d = lo + j;
        if (d < NN) {
            offsets[d] = sbase + excl[j];
            dinv[d] = rsqrtf((float)lhist[j] + 1.0f);
        }
    }
    if (b == NB - 1 && t == 0) offsets[NN] = sbase + cnt;   // sentinel == E
    for (int j = t; j < BW; j += 256) lcur[j] = 0;
    __syncthreads();
    for (int i = t; i < cnt; i += 256) {
        unsigned u = bp[i];
        int d = (int)(u >> 17);
        int slot = excl[d] + atomicAdd(&lcur[d], 1);
        csr_src[sbase + slot] = (int)(u & 0x1FFFF);
    }
}

// ---------------- GEMM: h[n][64] = (x[n][K] @ W[K][64]) * dinv[n], fp16 out ----

template <int K, int TM, bool INH>
__global__ __launch_bounds__(256) void k_gemm(const void* __restrict__ xin,
                                              const float* __restrict__ W,
                                              const float* __restrict__ dinv,
                                              __half* __restrict__ h) {
    __shared__ float Wl[K * 64];
    __shared__ float xs[TM * K];
    int t = threadIdx.x;
    int base = blockIdx.x * TM;
    for (int i = t; i < K * 16; i += 256)
        reinterpret_cast<float4*>(Wl)[i] = reinterpret_cast<const float4*>(W)[i];
    {
        const int NF4 = TM * K / 4;
        const int RF4 = K / 4;
        for (int i = t; i < NF4; i += 256) {
            int r = i / RF4, c = i - r * RF4;
            int gr = base + r; if (gr >= NN) gr = NN - 1;
            float4 v;
            if (INH) {
                uint2 u = reinterpret_cast<const uint2*>(xin)[(size_t)gr * RF4 + c];
                const __half2* hh = reinterpret_cast<const __half2*>(&u);
                float2 f01 = __half22float2(hh[0]);
                float2 f23 = __half22float2(hh[1]);
                v = make_float4(f01.x, f01.y, f23.x, f23.y);
            } else {
                v = reinterpret_cast<const float4*>(xin)[(size_t)gr * RF4 + c];
            }
            reinterpret_cast<float4*>(xs)[i] = v;
        }
    }
    __syncthreads();

    int lane = t & 63;
    int wid = t >> 6;
    const int RW = TM / 4;
    int r0 = wid * RW;
    float acc[RW];
#pragma unroll
    for (int r = 0; r < RW; r++) acc[r] = 0.f;

    for (int k = 0; k < K; k += 4) {
        float w0 = Wl[(k + 0) * 64 + lane];
        float w1 = Wl[(k + 1) * 64 + lane];
        float w2 = Wl[(k + 2) * 64 + lane];
        float w3 = Wl[(k + 3) * 64 + lane];
#pragma unroll
        for (int r = 0; r < RW; r++) {
            const float4 xv = *reinterpret_cast<const float4*>(&xs[(r0 + r) * K + k]);
            acc[r] = fmaf(xv.x, w0, acc[r]);
            acc[r] = fmaf(xv.y, w1, acc[r]);
            acc[r] = fmaf(xv.z, w2, acc[r]);
            acc[r] = fmaf(xv.w, w3, acc[r]);
        }
    }
    __half* hp = h + ((size_t)base + r0) * 64 + lane;
#pragma unroll
    for (int r = 0; r < RW; r++) {
        int row = base + r0 + r;
        if (row < NN) hp[r * 64] = __float2half(acc[r] * dinv[row]);
    }
}

// ---------------- aggregation V4 (R10 configuration) ----------------
// h pre-scaled by dinv[src], zero row at index NN. wave = 1 node; group g
// (8 lanes) owns slots 4g..4g+3; lane p loads uint4 = 8 fp16 feats -> one
// vmem instr fetches a whole 128B row; 4 gathers in flight per lane.

template <bool BN, bool OUTH>
__global__ __launch_bounds__(256) void k_agg(const __half* __restrict__ h,
                                             const int* __restrict__ csr_src,
                                             const int* __restrict__ offsets,
                                             const float* __restrict__ dinv,
                                             const float* __restrict__ bias,
                                             const float* __restrict__ g,
                                             const float* __restrict__ beta,
                                             const float* __restrict__ rm,
                                             const float* __restrict__ rv,
                                             void* __restrict__ outp) {
    int node = (blockIdx.x * 256 + threadIdx.x) >> 6;
    int lane = threadIdx.x & 63;
    int grp = lane >> 3;     // 0..7: slot group
    int p = lane & 7;        // uint4 index; feats 8p..8p+7
    int start = offsets[node];
    int len = offsets[node + 1] - start;
    const int* ep = csr_src + start;
    const uint4* hp4 = reinterpret_cast<const uint4*>(h);

    float a0 = 0.f, a1 = 0.f, a2 = 0.f, a3 = 0.f;
    float a4 = 0.f, a5 = 0.f, a6 = 0.f, a7 = 0.f;
    for (int i = 0; i < len; i += 32) {
        int s0, s1, s2, s3;
        {
            int sl = i + 4 * grp;
            int cl0 = sl     < len ? sl     : len - 1;
            int cl1 = sl + 1 < len ? sl + 1 : len - 1;
            int cl2 = sl + 2 < len ? sl + 2 : len - 1;
            int cl3 = sl + 3 < len ? sl + 3 : len - 1;
            int v0 = __builtin_nontemporal_load(ep + cl0);
            int v1 = __builtin_nontemporal_load(ep + cl1);
            int v2 = __builtin_nontemporal_load(ep + cl2);
            int v3 = __builtin_nontemporal_load(ep + cl3);
            s0 = (sl     < len) ? v0 : NN;   // zero row when masked
            s1 = (sl + 1 < len) ? v1 : NN;
            s2 = (sl + 2 < len) ? v2 : NN;
            s3 = (sl + 3 < len) ? v3 : NN;
        }
        uint4 d0 = hp4[(size_t)s0 * 8 + p];
        uint4 d1 = hp4[(size_t)s1 * 8 + p];
        uint4 d2 = hp4[(size_t)s2 * 8 + p];
        uint4 d3 = hp4[(size_t)s3 * 8 + p];
        const __half2* h0 = reinterpret_cast<const __half2*>(&d0);
        const __half2* h1 = reinterpret_cast<const __half2*>(&d1);
        const __half2* h2 = reinterpret_cast<const __half2*>(&d2);
        const __half2* h3 = reinterpret_cast<const __half2*>(&d3);
#pragma unroll
        for (int j = 0; j < 4; j++) {
            __half2 q = __hadd2(__hadd2(h0[j], h1[j]), __hadd2(h2[j], h3[j]));
            float2 f = __half22float2(q);
            if (j == 0) { a0 += f.x; a1 += f.y; }
            else if (j == 1) { a2 += f.x; a3 += f.y; }
            else if (j == 2) { a4 += f.x; a5 += f.y; }
            else { a6 += f.x; a7 += f.y; }
        }
    }
#pragma unroll
    for (int d = 8; d <= 32; d <<= 1) {
        a0 += __shfl_xor(a0, d); a1 += __shfl_xor(a1, d);
        a2 += __shfl_xor(a2, d); a3 += __shfl_xor(a3, d);
        a4 += __shfl_xor(a4, d); a5 += __shfl_xor(a5, d);
        a6 += __shfl_xor(a6, d); a7 += __shfl_xor(a7, d);
    }

    if (grp == 0) {
        uint4 sd = hp4[(size_t)node * 8 + p];
        const __half2* sh = reinterpret_cast<const __half2*>(&sd);
        float2 f;
        f = __half22float2(sh[0]); a0 += f.x; a1 += f.y;
        f = __half22float2(sh[1]); a2 += f.x; a3 += f.y;
        f = __half22float2(sh[2]); a4 += f.x; a5 += f.y;
        f = __half22float2(sh[3]); a6 += f.x; a7 += f.y;
        float di = dinv[node];
        float4 b0 = reinterpret_cast<const float4*>(bias)[2 * p];
        float4 b1 = reinterpret_cast<const float4*>(bias)[2 * p + 1];
        float r0 = fmaf(a0, di, b0.x), r1 = fmaf(a1, di, b0.y);
        float r2 = fmaf(a2, di, b0.z), r3 = fmaf(a3, di, b0.w);
        float r4 = fmaf(a4, di, b1.x), r5 = fmaf(a5, di, b1.y);
        float r6 = fmaf(a6, di, b1.z), r7 = fmaf(a7, di, b1.w);
        if (BN) {
            float4 g0 = reinterpret_cast<const float4*>(g)[2 * p];
            float4 g1 = reinterpret_cast<const float4*>(g)[2 * p + 1];
            float4 t0 = reinterpret_cast<const float4*>(beta)[2 * p];
            float4 t1 = reinterpret_cast<const float4*>(beta)[2 * p + 1];
            float4 m0 = reinterpret_cast<const float4*>(rm)[2 * p];
            float4 m1 = reinterpret_cast<const float4*>(rm)[2 * p + 1];
            float4 v0 = reinterpret_cast<const float4*>(rv)[2 * p];
            float4 v1 = reinterpret_cast<const float4*>(rv)[2 * p + 1];
            r0 = fmaxf(fmaf(r0 - m0.x, g0.x * rsqrtf(v0.x + 1e-5f), t0.x), 0.f);
            r1 = fmaxf(fmaf(r1 - m0.y, g0.y * rsqrtf(v0.y + 1e-5f), t0.y), 0.f);
            r2 = fmaxf(fmaf(r2 - m0.z, g0.z * rsqrtf(v0.z + 1e-5f), t0.z), 0.f);
            r3 = fmaxf(fmaf(r3 - m0.w, g0.w * rsqrtf(v0.w + 1e-5f), t0.w), 0.f);
            r4 = fmaxf(fmaf(r4 - m1.x, g1.x * rsqrtf(v1.x + 1e-5f), t1.x), 0.f);
            r5 = fmaxf(fmaf(r5 - m1.y, g1.y * rsqrtf(v1.y + 1e-5f), t1.y), 0.f);
            r6 = fmaxf(fmaf(r6 - m1.z, g1.z * rsqrtf(v1.z + 1e-5f), t1.z), 0.f);
            r7 = fmaxf(fmaf(r7 - m1.w, g1.w * rsqrtf(v1.w + 1e-5f), t1.w), 0.f);
        }
        if (OUTH) {
            __half2 o0; o0.x = __float2half_rn(r0); o0.y = __float2half_rn(r1);
            __half2 o1; o1.x = __float2half_rn(r2); o1.y = __float2half_rn(r3);
            __half2 o2; o2.x = __float2half_rn(r4); o2.y = __float2half_rn(r5);
            __half2 o3; o3.x = __float2half_rn(r6); o3.y = __float2half_rn(r7);
            uint4 o;
            o.x = *reinterpret_cast<unsigned*>(&o0);
            o.y = *reinterpret_cast<unsigned*>(&o1);
            o.z = *reinterpret_cast<unsigned*>(&o2);
            o.w = *reinterpret_cast<unsigned*>(&o3);
            reinterpret_cast<uint4*>(outp)[(size_t)node * 8 + p] = o;
        } else {
            reinterpret_cast<float4*>(outp)[(size_t)node * 16 + 2 * p] =
                make_float4(r0, r1, r2, r3);
            reinterpret_cast<float4*>(outp)[(size_t)node * 16 + 2 * p + 1] =
                make_float4(r4, r5, r6, r7);
        }
    }
}

// ---------------- launch ----------------

extern "C" void kernel_launch(void* const* d_in, const int* in_sizes, int n_in,
                              void* d_out, int out_size, void* d_ws, size_t ws_size,
                              hipStream_t stream) {
    const float* x = (const float*)d_in[0];
    const int* ei = (const int*)d_in[1];        // int32 per harness contract, [2][E]
    const float* W1 = (const float*)d_in[2];
    const float* b1 = (const float*)d_in[3];
    const float* W2 = (const float*)d_in[4];
    const float* b2 = (const float*)d_in[5];
    const float* W3 = (const float*)d_in[6];
    const float* b3 = (const float*)d_in[7];
    const float* g1 = (const float*)d_in[8];
    const float* be1 = (const float*)d_in[9];
    const float* rm1 = (const float*)d_in[10];
    const float* rv1 = (const float*)d_in[11];
    const float* g2 = (const float*)d_in[12];
    const float* be2 = (const float*)d_in[13];
    const float* rm2 = (const float*)d_in[14];
    const float* rv2 = (const float*)d_in[15];
    float* out = (float*)d_out;

    char* ws = (char*)d_ws;
    size_t off = 0;
    auto alloc = [&](size_t bytes) -> void* {
        void* p = ws + off;
        off = (off + bytes + 255) & ~(size_t)255;
        return p;
    };
    int* bcursor = (int*)alloc(256 * 4);
    int* offsets = (int*)alloc((size_t)(NN + 1) * 4);
    float* dinv = (float*)alloc((size_t)NN * 4);
    unsigned* binned = (unsigned*)alloc((size_t)NB * CAP * 4);
    int* csr_src = (int*)alloc((size_t)EE * 4);
    __half* h16 = (__half*)alloc((size_t)(NN + 1) * 64 * 2);   // +1 zero row
    __half* y16 = (__half*)alloc((size_t)(NN + 1) * 64 * 2);

    // zero: bucket cursors + zero rows at index NN (gather target for masked slots)
    hipMemsetAsync(bcursor, 0, 256 * 4, stream);
    hipMemsetAsync(h16 + (size_t)NN * 64, 0, 128, stream);
    hipMemsetAsync(y16 + (size_t)NN * 64, 0, 128, stream);

    k_binA<<<(EE + CHUNK - 1) / CHUNK, 256, 0, stream>>>(ei, bcursor, binned);
    k_sortB<<<NB, 256, 0, stream>>>(binned, bcursor, offsets, dinv, csr_src);

    // layer 1: K=128, TM=32, fp32 input
    k_gemm<K1, 32, false><<<NN / 32, 256, 0, stream>>>(x, W1, dinv, h16);
    k_agg<true, true><<<NN * 64 / 256, 256, 0, stream>>>(h16, csr_src, offsets, dinv,
                                                         b1, g1, be1, rm1, rv1, y16);
    // layer 2: K=64, TM=64, fp16 input
    k_gemm<HH, 64, true><<<(NN + 63) / 64, 256, 0, stream>>>(y16, W2, dinv, h16);
    k_agg<true, true><<<NN * 64 / 256, 256, 0, stream>>>(h16, csr_src, offsets, dinv,
                                                         b2, g2, be2, rm2, rv2, y16);
    // layer 3: fp32 output to d_out
    k_gemm<HH, 64, true><<<(NN + 63) / 64, 256, 0, stream>>>(y16, W3, dinv, h16);
    k_agg<false, false><<<NN * 64 / 256, 256, 0, stream>>>(h16, csr_src, offsets, dinv,
                                                           b3, b3, b3, b3, b3, out);
}